// Round 9
// baseline (149.901 us; speedup 1.0000x reference)
//
#include <hip/hip_runtime.h>
#include <hip/hip_bf16.h>

// Resonance tiling via fused block-GEMM on MFMA — barrier-free streaming.
// Math: per tile t, [y1,y2] = [x1,x2] * M_t, M_t = [[I,Psi],[Phi,I+Phi*Psi]]
// (128x128 bf16, built once by prep_kernel into d_ws).
// Round-8 lesson: __syncthreads => s_waitcnt vmcnt(0) drains prefetch loads
// AND stores at every chunk boundary. This round: NO LDS, NO barriers.
// A-fragments load straight from global (lane layout row=lane&15,
// k=(lane>>4)*8+reg -> 8 consecutive f32), cvt f32->bf16 in-register.
// Each wave = independent stream; block = fixed tile t, 4 waves = 2 row-subs
// x 2 N-halves; wn pair re-reads same A rows on the same CU (L2 absorbs).

typedef __attribute__((ext_vector_type(8))) short bf16x8;
typedef __attribute__((ext_vector_type(4))) float f32x4;

static __device__ __forceinline__ unsigned short f2bf(float f) {
    unsigned u = __builtin_bit_cast(unsigned, f);
    unsigned r = 0x7FFFu + ((u >> 16) & 1u);     // round-to-nearest-even
    return (unsigned short)((u + r) >> 16);
}

static __device__ __forceinline__ short hwbf(float f) {
    __hip_bfloat16 h = __float2bfloat16(f);       // hardware cvt
    return __builtin_bit_cast(short, h);
}

// ---------------- pre-kernel: build M_t^T (bf16) ----------------
__global__ __launch_bounds__(256)
void prep_kernel(const float4* __restrict__ phi,
                 const float4* __restrict__ psi,
                 unsigned short* __restrict__ mt) {
    __shared__ float Phi[64][64];
    __shared__ float Psi[64][64];
    const int t   = blockIdx.x;          // 0..7
    const int tid = threadIdx.x;
    const int i   = tid >> 4, j = tid & 15;

    {   // Hamilton 4x4 block (row-vec convention, matches reference)
        float4 w = phi[t * 256 + i * 16 + j];
        float a = w.x, b = w.y, c = w.z, d = w.w;
        Phi[4*i+0][4*j+0]= a; Phi[4*i+0][4*j+1]= b; Phi[4*i+0][4*j+2]= c; Phi[4*i+0][4*j+3]= d;
        Phi[4*i+1][4*j+0]=-b; Phi[4*i+1][4*j+1]= a; Phi[4*i+1][4*j+2]=-d; Phi[4*i+1][4*j+3]= c;
        Phi[4*i+2][4*j+0]=-c; Phi[4*i+2][4*j+1]= d; Phi[4*i+2][4*j+2]= a; Phi[4*i+2][4*j+3]=-b;
        Phi[4*i+3][4*j+0]=-d; Phi[4*i+3][4*j+1]=-c; Phi[4*i+3][4*j+2]= b; Phi[4*i+3][4*j+3]= a;
        float4 v = psi[(8 + t) * 256 + i * 16 + j];
        a = v.x; b = v.y; c = v.z; d = v.w;
        Psi[4*i+0][4*j+0]= a; Psi[4*i+0][4*j+1]= b; Psi[4*i+0][4*j+2]= c; Psi[4*i+0][4*j+3]= d;
        Psi[4*i+1][4*j+0]=-b; Psi[4*i+1][4*j+1]= a; Psi[4*i+1][4*j+2]=-d; Psi[4*i+1][4*j+3]= c;
        Psi[4*i+2][4*j+0]=-c; Psi[4*i+2][4*j+1]= d; Psi[4*i+2][4*j+2]= a; Psi[4*i+2][4*j+3]=-b;
        Psi[4*i+3][4*j+0]=-d; Psi[4*i+3][4*j+1]=-c; Psi[4*i+3][4*j+2]= b; Psi[4*i+3][4*j+3]= a;
    }
    __syncthreads();

    unsigned short* m = mt + t * 16384;   // MT[n][k] = M[k][n]
    for (int e = tid; e < 16384; e += 256) {
        const int n = e >> 7, k = e & 127;
        if (n >= 64 && k >= 64) continue;
        float v;
        if (k < 64 && n < 64)       v = (k == n) ? 1.f : 0.f;   // M11 = I
        else if (k >= 64)           v = Phi[k - 64][n];          // M21 = Phi
        else                        v = Psi[k][n - 64];          // M12 = Psi
        m[e] = f2bf(v);
    }
    // M22 = I + Phi@Psi
    const int r = tid & 63, c0 = (tid >> 6) * 16;
    float pk[16];
#pragma unroll
    for (int cc = 0; cc < 16; ++cc) pk[cc] = 0.f;
    for (int k = 0; k < 64; ++k) {
        const float fr = Phi[r][k];
#pragma unroll
        for (int cc = 0; cc < 16; ++cc) pk[cc] = fmaf(fr, Psi[k][c0 + cc], pk[cc]);
    }
#pragma unroll
    for (int cc = 0; cc < 16; ++cc) {
        const int c = c0 + cc;
        m[(64 + c) * 128 + (64 + r)] = f2bf(((r == c) ? 1.f : 0.f) + pk[cc]);
    }
}

// ------------- main: barrier-free per-wave streaming GEMM -------------
// wave unit: 16 rows x 64 N-cols of one tile. block = tile t, 4 waves
// (wm = 16-row sub of a 32-row group, wn = N-half). Grid-stride on groups.
__global__ __launch_bounds__(256)
void gemm_kernel(const float* __restrict__ x,
                 const unsigned short* __restrict__ mt,
                 float* __restrict__ out,
                 int ngroups) {
    const int tid  = threadIdx.x;
    const int lane = tid & 63, wid = tid >> 6;
    const int wm = wid >> 1, wn = wid & 1;
    const int ln = lane & 15, lk = lane >> 4;
    const int t  = blockIdx.x & 7;
    const int gs = gridDim.x >> 3;

    // B fragments (M^T, L2-hot): b[fn][ks] -> 64 VGPR
    bf16x8 b[4][4];
    {
        const unsigned short* mtt = mt + t * 16384;
#pragma unroll
        for (int fn = 0; fn < 4; ++fn)
#pragma unroll
            for (int ks = 0; ks < 4; ++ks) {
                const int n = wn * 64 + fn * 16 + ln;
                const int k = ks * 32 + lk * 8;
                b[fn][ks] = *(const bf16x8*)(mtt + n * 128 + k);
            }
    }

    const int cb = wn * 512 + t * 64 + ln;     // out f32 col base (+ fn*16)
    const int ca = t * 64 + lk * 8;            // A f32 col base (+ks pattern)

    for (int g = blockIdx.x >> 3; g < ngroups; g += gs) {
        const size_t rA = (size_t)g * 32 + wm * 16 + ln;   // this lane's A row
        const float* xr = x + rA * 1024 + ca;

        // A: 8x dwordx4 straight from global (8 consecutive f32 per ks)
        const float4 L0 = *(const float4*)(xr + 0);
        const float4 L1 = *(const float4*)(xr + 4);
        const float4 L2 = *(const float4*)(xr + 32);
        const float4 L3 = *(const float4*)(xr + 36);
        const float4 L4 = *(const float4*)(xr + 512);
        const float4 L5 = *(const float4*)(xr + 516);
        const float4 L6 = *(const float4*)(xr + 544);
        const float4 L7 = *(const float4*)(xr + 548);

        // cvt to bf16 fragments (hardware cvt)
        bf16x8 af[4];
#define PACK(kk, A, B) { \
        af[kk][0] = hwbf(A.x); af[kk][1] = hwbf(A.y); \
        af[kk][2] = hwbf(A.z); af[kk][3] = hwbf(A.w); \
        af[kk][4] = hwbf(B.x); af[kk][5] = hwbf(B.y); \
        af[kk][6] = hwbf(B.z); af[kk][7] = hwbf(B.w); }
        PACK(0, L0, L1) PACK(1, L2, L3) PACK(2, L4, L5) PACK(3, L6, L7)
#undef PACK

        // MFMA: 16 x 16x16x32
        f32x4 acc[4];
#pragma unroll
        for (int fn = 0; fn < 4; ++fn) acc[fn] = (f32x4)(0.f);
#pragma unroll
        for (int ks = 0; ks < 4; ++ks)
#pragma unroll
            for (int fn = 0; fn < 4; ++fn)
                acc[fn] = __builtin_amdgcn_mfma_f32_16x16x32_bf16(
                    af[ks], b[fn][ks], acc[fn], 0, 0, 0);

        // stores: D lane map col=ln, row=lk*4+rr
        const size_t rO = (size_t)g * 32 + wm * 16 + lk * 4;
#pragma unroll
        for (int fn = 0; fn < 4; ++fn)
#pragma unroll
            for (int rr = 0; rr < 4; ++rr)
                out[(rO + rr) * 1024 + cb + fn * 16] = acc[fn][rr];
    }
}

extern "C" void kernel_launch(void* const* d_in, const int* in_sizes, int n_in,
                              void* d_out, int out_size, void* d_ws, size_t ws_size,
                              hipStream_t stream) {
    const float* x    = (const float*)d_in[0];
    const float4* phi = (const float4*)d_in[1];
    const float4* psi = (const float4*)d_in[2];
    unsigned short* mt = (unsigned short*)d_ws;    // 8*128*128 bf16 = 256KB
    float* out = (float*)d_out;

    const int rows    = in_sizes[0] / 1024;        // 65536
    const int ngroups = rows / 32;                 // 2048 (32-row groups/tile)
    const int blocks  = 8 * 96;                    // 3 blocks/CU, grid-stride

    prep_kernel<<<8, 256, 0, stream>>>(phi, psi, mt);
    gemm_kernel<<<blocks, 256, 0, stream>>>(x, mt, out, ngroups);
}

// Round 11
// 124.689 us; speedup vs baseline: 1.2022x; 1.2022x over previous
//
#include <hip/hip_runtime.h>
#include <hip/hip_bf16.h>

// Resonance tiling via fused block-GEMM on MFMA — barrier-free streaming v2.
// Math: per tile t, [y1,y2] = [x1,x2] * M_t, M_t = [[I,Psi],[Phi,I+Phi*Psi]]
// (128x128 bf16, built once by prep_kernel into d_ws).
//
// Round-9 lesson: vmcnt counts STORES in issue order — the cvt's waitcnt
// each iteration was draining the previous iteration's 16 HBM stores
// (loads were issued after stores). Fix: issue next group's loads BEFORE
// this group's stores -> waitcnt becomes vmcnt(#stores), stores never
// drain the pipe. Also: operand-swapped MFMA (M^T as A, x as B) => D lane
// map (col=x-row, row=n): each lane holds 4 consecutive n -> float4 stores
// (4 instead of 16), nontemporal (out never re-read; keep x in L2/L3).
// Round-10 fix: nontemporal builtin needs ext_vector type, not HIP float4.

typedef __attribute__((ext_vector_type(8))) short bf16x8;
typedef __attribute__((ext_vector_type(4))) float f32x4;

static __device__ __forceinline__ unsigned short f2bf(float f) {
    unsigned u = __builtin_bit_cast(unsigned, f);
    unsigned r = 0x7FFFu + ((u >> 16) & 1u);     // round-to-nearest-even
    return (unsigned short)((u + r) >> 16);
}

static __device__ __forceinline__ short hwbf(float f) {
    __hip_bfloat16 h = __float2bfloat16(f);       // hardware v_cvt
    return __builtin_bit_cast(short, h);
}

// ---------------- pre-kernel: build M_t^T (bf16) ----------------
__global__ __launch_bounds__(256)
void prep_kernel(const float4* __restrict__ phi,
                 const float4* __restrict__ psi,
                 unsigned short* __restrict__ mt) {
    __shared__ float Phi[64][64];
    __shared__ float Psi[64][64];
    const int t   = blockIdx.x;          // 0..7
    const int tid = threadIdx.x;
    const int i   = tid >> 4, j = tid & 15;

    {   // Hamilton 4x4 block (row-vec convention, matches reference)
        float4 w = phi[t * 256 + i * 16 + j];
        float a = w.x, b = w.y, c = w.z, d = w.w;
        Phi[4*i+0][4*j+0]= a; Phi[4*i+0][4*j+1]= b; Phi[4*i+0][4*j+2]= c; Phi[4*i+0][4*j+3]= d;
        Phi[4*i+1][4*j+0]=-b; Phi[4*i+1][4*j+1]= a; Phi[4*i+1][4*j+2]=-d; Phi[4*i+1][4*j+3]= c;
        Phi[4*i+2][4*j+0]=-c; Phi[4*i+2][4*j+1]= d; Phi[4*i+2][4*j+2]= a; Phi[4*i+2][4*j+3]=-b;
        Phi[4*i+3][4*j+0]=-d; Phi[4*i+3][4*j+1]=-c; Phi[4*i+3][4*j+2]= b; Phi[4*i+3][4*j+3]= a;
        float4 v = psi[(8 + t) * 256 + i * 16 + j];
        a = v.x; b = v.y; c = v.z; d = v.w;
        Psi[4*i+0][4*j+0]= a; Psi[4*i+0][4*j+1]= b; Psi[4*i+0][4*j+2]= c; Psi[4*i+0][4*j+3]= d;
        Psi[4*i+1][4*j+0]=-b; Psi[4*i+1][4*j+1]= a; Psi[4*i+1][4*j+2]=-d; Psi[4*i+1][4*j+3]= c;
        Psi[4*i+2][4*j+0]=-c; Psi[4*i+2][4*j+1]= d; Psi[4*i+2][4*j+2]= a; Psi[4*i+2][4*j+3]=-b;
        Psi[4*i+3][4*j+0]=-d; Psi[4*i+3][4*j+1]=-c; Psi[4*i+3][4*j+2]= b; Psi[4*i+3][4*j+3]= a;
    }
    __syncthreads();

    unsigned short* m = mt + t * 16384;   // MT[n][k] = M[k][n]
    for (int e = tid; e < 16384; e += 256) {
        const int n = e >> 7, k = e & 127;
        if (n >= 64 && k >= 64) continue;
        float v;
        if (k < 64 && n < 64)       v = (k == n) ? 1.f : 0.f;   // M11 = I
        else if (k >= 64)           v = Phi[k - 64][n];          // M21 = Phi
        else                        v = Psi[k][n - 64];          // M12 = Psi
        m[e] = f2bf(v);
    }
    // M22 = I + Phi@Psi
    const int r = tid & 63, c0 = (tid >> 6) * 16;
    float pk[16];
#pragma unroll
    for (int cc = 0; cc < 16; ++cc) pk[cc] = 0.f;
    for (int k = 0; k < 64; ++k) {
        const float fr = Phi[r][k];
#pragma unroll
        for (int cc = 0; cc < 16; ++cc) pk[cc] = fmaf(fr, Psi[k][c0 + cc], pk[cc]);
    }
#pragma unroll
    for (int cc = 0; cc < 16; ++cc) {
        const int c = c0 + cc;
        m[(64 + c) * 128 + (64 + r)] = f2bf(((r == c) ? 1.f : 0.f) + pk[cc]);
    }
}

// ------------- main: barrier-free per-wave streaming GEMM -------------
// wave unit: 16 rows x 64 n-cols of one tile (operand-swapped MFMA).
// block = tile t, 4 waves (wm: 16-row sub, wn: n-half). Grid-stride.
__global__ __launch_bounds__(256)
void gemm_kernel(const float* __restrict__ x,
                 const unsigned short* __restrict__ mt,
                 float* __restrict__ out,
                 int ngroups) {
    const int tid  = threadIdx.x;
    const int lane = tid & 63, wid = tid >> 6;
    const int wm = wid >> 1, wn = wid & 1;
    const int ln = lane & 15, lk = lane >> 4;
    const int t  = blockIdx.x & 7;
    const int gs = gridDim.x >> 3;

    // M^T fragments as the A-operand: a[fn][ks] (A row = n, 8 contiguous k)
    bf16x8 a[4][4];
    {
        const unsigned short* mtt = mt + t * 16384;
#pragma unroll
        for (int fn = 0; fn < 4; ++fn)
#pragma unroll
            for (int ks = 0; ks < 4; ++ks)
                a[fn][ks] = *(const bf16x8*)(mtt + (wn * 64 + fn * 16 + ln) * 128
                                                 + ks * 32 + lk * 8);
    }

    const int ca  = t * 64 + lk * 8;             // x f32 col base (+ks pattern)
    const int cob = (wn ? 512 : 0) + t * 64;     // out f32 col base (+fn*16+lk*4)

    float4 L[8];
    auto issue = [&](int gg) {
        const float* xr = x + ((size_t)gg * 32 + wm * 16 + ln) * 1024 + ca;
        L[0] = *(const float4*)(xr + 0);   L[1] = *(const float4*)(xr + 4);
        L[2] = *(const float4*)(xr + 32);  L[3] = *(const float4*)(xr + 36);
        L[4] = *(const float4*)(xr + 512); L[5] = *(const float4*)(xr + 516);
        L[6] = *(const float4*)(xr + 544); L[7] = *(const float4*)(xr + 548);
    };

    int g = blockIdx.x >> 3;
    if (g < ngroups) issue(g);

    while (g < ngroups) {
        // cvt L -> B-operand fragments (col = x-row = ln, 8 contiguous k)
        bf16x8 bx[4];
#define PACK(kk, A, B) { \
        bx[kk][0] = hwbf(A.x); bx[kk][1] = hwbf(A.y); \
        bx[kk][2] = hwbf(A.z); bx[kk][3] = hwbf(A.w); \
        bx[kk][4] = hwbf(B.x); bx[kk][5] = hwbf(B.y); \
        bx[kk][6] = hwbf(B.z); bx[kk][7] = hwbf(B.w); }
        PACK(0, L[0], L[1]) PACK(1, L[2], L[3])
        PACK(2, L[4], L[5]) PACK(3, L[6], L[7])
#undef PACK

        // prefetch next group's loads NOW — before this group's stores,
        // so the next waitcnt never waits on store completion.
        const int gn = g + gs;
        if (gn < ngroups) issue(gn);

        // MFMA: D = M^T-frags (A) x x-frags (B); 16 x 16x16x32
        f32x4 acc[4];
#pragma unroll
        for (int fn = 0; fn < 4; ++fn) acc[fn] = (f32x4)(0.f);
#pragma unroll
        for (int ks = 0; ks < 4; ++ks)
#pragma unroll
            for (int fn = 0; fn < 4; ++fn)
                acc[fn] = __builtin_amdgcn_mfma_f32_16x16x32_bf16(
                    a[fn][ks], bx[ks], acc[fn], 0, 0, 0);

        // stores: lane holds x-row = ln, n = fn*16 + lk*4 + reg -> f32x4
        {
            float* orow = out + ((size_t)g * 32 + wm * 16 + ln) * 1024
                              + cob + lk * 4;
#pragma unroll
            for (int fn = 0; fn < 4; ++fn)
                __builtin_nontemporal_store(acc[fn], (f32x4*)(orow + fn * 16));
        }

        g = gn;
    }
}

extern "C" void kernel_launch(void* const* d_in, const int* in_sizes, int n_in,
                              void* d_out, int out_size, void* d_ws, size_t ws_size,
                              hipStream_t stream) {
    const float* x    = (const float*)d_in[0];
    const float4* phi = (const float4*)d_in[1];
    const float4* psi = (const float4*)d_in[2];
    unsigned short* mt = (unsigned short*)d_ws;    // 8*128*128 bf16 = 256KB
    float* out = (float*)d_out;

    const int rows    = in_sizes[0] / 1024;        // 65536
    const int ngroups = rows / 32;                 // 2048 (32-row groups/tile)
    const int blocks  = 8 * 96;                    // 3 blocks/CU, grid-stride

    prep_kernel<<<8, 256, 0, stream>>>(phi, psi, mt);
    gemm_kernel<<<blocks, 256, 0, stream>>>(x, mt, out, ngroups);
}